// Round 2
// baseline (424.526 us; speedup 1.0000x reference)
//
#include <hip/hip_runtime.h>
#include <math.h>

// x [64,4096,64] fp32, embedding [512,64] fp32
#define N_ROWS   262144
#define DIM      64
#define KCODES   512
#define MT       64          // rows per block
#define NTHREADS 256
#define XS_STRIDE 68         // floats  (272 B, 16-B aligned, conflict-min)
#define ES_STRIDE 72         // bf16    (144 B, 16-B aligned, conflict-min)
#define MARGIN   2e-3f       // flag threshold; split error bound ~5e-4

typedef float f32x4 __attribute__((ext_vector_type(4)));
typedef short s16x8 __attribute__((ext_vector_type(8)));

// ws layout (bytes):
//   0      esq[512]   f32     (2048)
//   2048   counts[512] int    (2048)
//   4096   loss f32           (4)
//   4608   eh[512*64] bf16    (65536)
//   70144  el[512*64] bf16    (65536)
//   135680 flagmask[8192] u32 (32768)   bit per row
// total ~168 KB

__device__ __forceinline__ unsigned short f2bf(float f) {
    unsigned u = __float_as_uint(f);
    unsigned r = u + 0x7fffu + ((u >> 16) & 1u);   // RNE
    return (unsigned short)(r >> 16);
}
__device__ __forceinline__ float bf2f(unsigned short h) {
    return __uint_as_float(((unsigned)h) << 16);
}

__global__ __launch_bounds__(512) void vq_prep(const float* __restrict__ emb,
                                               float* __restrict__ esq,
                                               int* __restrict__ counts,
                                               float* __restrict__ lossp,
                                               unsigned short* __restrict__ eh,
                                               unsigned short* __restrict__ el,
                                               unsigned* __restrict__ mask) {
    int k = threadIdx.x;                       // 512 threads, 1 block
    const float* e = emb + (size_t)k * DIM;
    float s = 0.f;
    #pragma unroll
    for (int d = 0; d < DIM; ++d) s += e[d] * e[d];   // identical to round-1 prep
    esq[k] = s;
    counts[k] = 0;
    #pragma unroll
    for (int d = 0; d < DIM; ++d) {
        float v = e[d];
        unsigned short h = f2bf(v);
        eh[k * DIM + d] = h;
        el[k * DIM + d] = f2bf(v - bf2f(h));
    }
    #pragma unroll
    for (int i = 0; i < 16; ++i) mask[k * 16 + i] = 0u;   // 8192 words
    if (k == 0) *lossp = 0.f;
}

__global__ __launch_bounds__(NTHREADS, 2) void vq_main(
    const float* __restrict__ x, const float* __restrict__ emb,
    const float* __restrict__ g_esq,
    const unsigned short* __restrict__ eh_g, const unsigned short* __restrict__ el_g,
    int* __restrict__ g_counts, float* __restrict__ g_loss,
    unsigned* __restrict__ g_mask, float* __restrict__ out)
{
    __shared__ float xs[MT * XS_STRIDE];                  // 17.4 KB, row-major x tile
    __shared__ unsigned short ehs[128 * ES_STRIDE];       // 18.4 KB codebook chunk hi
    __shared__ unsigned short els[128 * ES_STRIDE];       // 18.4 KB codebook chunk lo
    __shared__ float esq_s[KCODES];                       // 2 KB
    __shared__ int   idx_s[MT];
    __shared__ int   flg_s[MT];
    __shared__ float wred[4];

    const int tid  = threadIdx.x;
    const int R0   = blockIdx.x * MT;
    const int w    = tid >> 6;          // wave 0..3 -> rows w*16..w*16+15
    const int lane = tid & 63;
    const int m    = lane & 15;         // A-frag row / B-frag col / C col
    const int q    = lane >> 4;         // quad: k-run selector / C row group

    // ---- stage x tile (coalesced float4, row-major stride 68) ----
    #pragma unroll
    for (int i = 0; i < 4; ++i) {
        int flat = tid + NTHREADS * i;          // 0..1023
        int r  = flat >> 4;
        int qc = flat & 15;
        f32x4 v = *(const f32x4*)&x[(size_t)(R0 + r) * DIM + 4 * qc];
        *(f32x4*)&xs[r * XS_STRIDE + 4 * qc] = v;
    }
    esq_s[tid]       = g_esq[tid];
    esq_s[tid + 256] = g_esq[tid + 256];
    __syncthreads();

    // ---- A-frags (register-resident): rows w*16+m, k = kc*32 + q*8 + t ----
    s16x8 axh[2], axl[2];
    const int lrow = w * 16 + m;
    #pragma unroll
    for (int kc = 0; kc < 2; ++kc) {
        const float* px = &xs[lrow * XS_STRIDE + kc * 32 + q * 8];
        s16x8 h, l;
        #pragma unroll
        for (int t = 0; t < 8; ++t) {
            float v = px[t];
            unsigned short hb = f2bf(v);
            h[t] = (short)hb;
            l[t] = (short)f2bf(v - bf2f(hb));
        }
        axh[kc] = h; axl[kc] = l;
    }

    f32x4 acc[32];                                      // 512 codes per 16 rows
    #pragma unroll
    for (int a = 0; a < 32; ++a) acc[a] = (f32x4){0.f, 0.f, 0.f, 0.f};

    // ---- 4 chunks of 128 codes ----
    for (int c = 0; c < 4; ++c) {
        if (c) __syncthreads();                          // prior chunk reads done
        #pragma unroll
        for (int i = 0; i < 4; ++i) {                    // stage chunk: coalesced 16B
            int ch = tid + NTHREADS * i;                 // 0..1023
            int rl = ch >> 3, off = (ch & 7) * 8;
            size_t gofs = (size_t)(c * 128 + rl) * DIM + off;
            *(s16x8*)&ehs[rl * ES_STRIDE + off] = *(const s16x8*)&eh_g[gofs];
            *(s16x8*)&els[rl * ES_STRIDE + off] = *(const s16x8*)&el_g[gofs];
        }
        __syncthreads();
        #pragma unroll
        for (int ct = 0; ct < 8; ++ct) {
            const int a = c * 8 + ct;
            #pragma unroll
            for (int kc = 0; kc < 2; ++kc) {
                const int bofs = (ct * 16 + m) * ES_STRIDE + kc * 32 + q * 8;
                s16x8 bh = *(const s16x8*)&ehs[bofs];
                s16x8 bl = *(const s16x8*)&els[bofs];
                acc[a] = __builtin_amdgcn_mfma_f32_16x16x32_bf16(axh[kc], bh, acc[a], 0, 0, 0);
                acc[a] = __builtin_amdgcn_mfma_f32_16x16x32_bf16(axl[kc], bh, acc[a], 0, 0, 0);
                acc[a] = __builtin_amdgcn_mfma_f32_16x16x32_bf16(axh[kc], bl, acc[a], 0, 0, 0);
            }
        }
    }

    // ---- per-row argmin + second-best (C layout: row=q*4+r, col=a*16+m) ----
    float b1[4], b2[4]; int i1[4];
    #pragma unroll
    for (int r = 0; r < 4; ++r) { b1[r] = 3.4e38f; b2[r] = 3.4e38f; i1[r] = 0; }
    #pragma unroll
    for (int a = 0; a < 32; ++a) {
        int col = a * 16 + m;                            // ascending in a
        float e2 = esq_s[col];
        #pragma unroll
        for (int r = 0; r < 4; ++r) {
            float dist = e2 - 2.f * acc[a][r];
            if (dist < b1[r]) { b2[r] = b1[r]; b1[r] = dist; i1[r] = col; }
            else if (dist < b2[r]) b2[r] = dist;
        }
    }
    #pragma unroll
    for (int s = 1; s < 16; s <<= 1) {                   // butterfly within 16-lane group
        #pragma unroll
        for (int r = 0; r < 4; ++r) {
            float ob1 = __shfl_xor(b1[r], s);
            int   oi1 = __shfl_xor(i1[r], s);
            float ob2 = __shfl_xor(b2[r], s);
            bool owin = (ob1 < b1[r]) || (ob1 == b1[r] && oi1 < i1[r]);
            float lb1 = owin ? b1[r] : ob1;              // loser's best = new 2nd candidate
            b2[r] = fminf(fminf(b2[r], ob2), lb1);
            if (owin) { b1[r] = ob1; i1[r] = oi1; }
        }
    }
    if (m == 0) {
        #pragma unroll
        for (int r = 0; r < 4; ++r) {
            int lrw = w * 16 + q * 4 + r;
            idx_s[lrw] = i1[r];
            int f = (b2[r] - b1[r] < MARGIN) ? 1 : 0;
            flg_s[lrw] = f;
            if (f) {
                int grow = R0 + lrw;
                atomicOr(&g_mask[grow >> 5], 1u << (grow & 31));
            } else {
                atomicAdd(&g_counts[i1[r]], 1);
            }
        }
    }
    __syncthreads();

    // ---- epilogue: q_st + loss for unflagged rows (round-1 op order) ----
    const int r  = tid >> 2;
    const int d0 = (tid & 3) * 16;
    float lpart = 0.f;
    if (!flg_s[r]) {
        const int ki = idx_s[r];
        const float* erow = emb + (size_t)ki * DIM;
        #pragma unroll
        for (int s4 = 0; s4 < 4; ++s4) {
            int d = d0 + 4 * s4;
            f32x4 e4 = *(const f32x4*)&erow[d];
            float xv0 = xs[r * XS_STRIDE + d + 0];
            float xv1 = xs[r * XS_STRIDE + d + 1];
            float xv2 = xs[r * XS_STRIDE + d + 2];
            float xv3 = xs[r * XS_STRIDE + d + 3];
            float f0 = e4.x - xv0, f1 = e4.y - xv1, f2 = e4.z - xv2, f3 = e4.w - xv3;
            f32x4 o = {xv0 + f0, xv1 + f1, xv2 + f2, xv3 + f3};
            *(f32x4*)&out[(size_t)(R0 + r) * DIM + d] = o;
            lpart += f0*f0 + f1*f1 + f2*f2 + f3*f3;
        }
    }
    #pragma unroll
    for (int off = 32; off > 0; off >>= 1) lpart += __shfl_down(lpart, off);
    if ((tid & 63) == 0) wred[tid >> 6] = lpart;
    __syncthreads();
    if (tid == 0) atomicAdd(g_loss, wred[0] + wred[1] + wred[2] + wred[3]);
}

// Exact fp32 re-resolution of flagged rows — replicates round-1 math bit-for-bit.
__global__ __launch_bounds__(256) void vq_cleanup(
    const float* __restrict__ x, const float* __restrict__ emb,
    const float* __restrict__ g_esq, int* __restrict__ g_counts,
    float* __restrict__ g_loss, const unsigned* __restrict__ g_mask,
    float* __restrict__ out)
{
    int w    = blockIdx.x * 4 + (threadIdx.x >> 6);   // 0..4095, 64 rows each
    int lane = threadIdx.x & 63;
    unsigned m0 = g_mask[w * 2], m1 = g_mask[w * 2 + 1];
    unsigned long long bits = ((unsigned long long)m1 << 32) | m0;
    while (bits) {
        int b = __ffsll((unsigned long long)bits) - 1;
        bits &= bits - 1;
        int row = w * 64 + b;
        const float* xr = &x[(size_t)row * DIM];
        float best = 3.4e38f; int bidx = 0;
        #pragma unroll
        for (int j = 0; j < 8; ++j) {
            int c = lane * 8 + j;
            const float* er = &emb[(size_t)c * DIM];
            float dot = 0.f;
            #pragma unroll
            for (int d = 0; d < DIM; ++d) dot = fmaf(xr[d], er[d], dot);
            float dist = g_esq[c] - 2.f * dot;         // round-1 formula/order
            if (dist < best) { best = dist; bidx = c; }
        }
        #pragma unroll
        for (int s = 1; s < 64; s <<= 1) {
            float ob = __shfl_xor(best, s);
            int   oi = __shfl_xor(bidx, s);
            if (ob < best || (ob == best && oi < bidx)) { best = ob; bidx = oi; }
        }
        float xv = xr[lane];
        float ev = emb[(size_t)bidx * DIM + lane];
        float f  = ev - xv;
        out[(size_t)row * DIM + lane] = xv + f;
        float lp = f * f;
        #pragma unroll
        for (int s = 1; s < 64; s <<= 1) lp += __shfl_xor(lp, s);
        if (lane == 0) {
            atomicAdd(g_loss, lp);
            atomicAdd(&g_counts[bidx], 1);
        }
    }
}

__global__ __launch_bounds__(512) void vq_final(const int* __restrict__ counts,
                                                const float* __restrict__ lossp,
                                                float* __restrict__ out) {
    __shared__ float red[8];
    int k = threadIdx.x;
    float p = (float)counts[k] * (1.f / 262144.f);
    float t = p * logf(p + 1e-10f);
    #pragma unroll
    for (int off = 32; off > 0; off >>= 1) t += __shfl_down(t, off);
    if ((k & 63) == 0) red[k >> 6] = t;
    __syncthreads();
    if (k == 0) {
        float s = 0.f;
        #pragma unroll
        for (int i = 0; i < 8; ++i) s += red[i];
        out[16777216] = (*lossp) * (0.25f / 16777216.f);
        out[16777217] = expf(-s);
    }
}

extern "C" void kernel_launch(void* const* d_in, const int* in_sizes, int n_in,
                              void* d_out, int out_size, void* d_ws, size_t ws_size,
                              hipStream_t stream) {
    const float* x   = (const float*)d_in[0];
    const float* emb = (const float*)d_in[1];
    float* out = (float*)d_out;

    char* ws = (char*)d_ws;
    float*          esq    = (float*)(ws + 0);
    int*            counts = (int*)(ws + 2048);
    float*          lossp  = (float*)(ws + 4096);
    unsigned short* eh     = (unsigned short*)(ws + 4608);
    unsigned short* el     = (unsigned short*)(ws + 70144);
    unsigned*       mask   = (unsigned*)(ws + 135680);

    vq_prep<<<1, 512, 0, stream>>>(emb, esq, counts, lossp, eh, el, mask);
    vq_main<<<N_ROWS / MT, NTHREADS, 0, stream>>>(x, emb, esq, eh, el,
                                                  counts, lossp, mask, out);
    vq_cleanup<<<1024, 256, 0, stream>>>(x, emb, esq, counts, lossp, mask, out);
    vq_final<<<1, 512, 0, stream>>>(counts, lossp, out);
}

// Round 3
// 264.270 us; speedup vs baseline: 1.6064x; 1.6064x over previous
//
#include <hip/hip_runtime.h>
#include <math.h>

// x [64,4096,64] fp32, embedding [512,64] fp32
#define N_ROWS   262144
#define DIM      64
#define KCODES   512
#define MT       64          // rows per block
#define NTHREADS 256
#define NBLOCKS  (N_ROWS / MT)   // 4096
#define XS_STRIDE 68         // floats  (272 B, 16-B aligned)
#define ES_STRIDE 72         // bf16    (144 B, 16-B aligned)
#define MARGIN   2e-3f       // flag threshold; split error bound ~5e-4

typedef float f32x4 __attribute__((ext_vector_type(4)));
typedef short s16x8 __attribute__((ext_vector_type(8)));

// ws layout (bytes):
//   0       esq[512]        f32   (2048)
//   2048    counts[512]     int   (2048)
//   4096    lossAdj         f32   (4)      cleanup's rare additions
//   4608    eh[512*64]      bf16  (65536)
//   70144   el[512*64]      bf16  (65536)
//   135680  flagmask[8192]  u32   (32768)  bit per row
//   168448  idx[262144]     u16   (524288)
//   692736  lossPart[4096]  f32   (16384)
// total ~709 KB

__device__ __forceinline__ unsigned short f2bf(float f) {
    unsigned u = __float_as_uint(f);
    unsigned r = u + 0x7fffu + ((u >> 16) & 1u);   // RNE
    return (unsigned short)(r >> 16);
}
__device__ __forceinline__ float bf2f(unsigned short h) {
    return __uint_as_float(((unsigned)h) << 16);
}

__global__ __launch_bounds__(512) void vq_prep(const float* __restrict__ emb,
                                               float* __restrict__ esq,
                                               int* __restrict__ counts,
                                               float* __restrict__ lossAdj,
                                               unsigned short* __restrict__ eh,
                                               unsigned short* __restrict__ el,
                                               unsigned* __restrict__ mask) {
    int k = threadIdx.x;                       // 512 threads, 1 block
    const float* e = emb + (size_t)k * DIM;
    float s = 0.f;
    #pragma unroll
    for (int d = 0; d < DIM; ++d) s += e[d] * e[d];   // identical to round-1 prep
    esq[k] = s;
    counts[k] = 0;
    #pragma unroll
    for (int d = 0; d < DIM; ++d) {
        float v = e[d];
        unsigned short h = f2bf(v);
        eh[k * DIM + d] = h;
        el[k * DIM + d] = f2bf(v - bf2f(h));
    }
    #pragma unroll
    for (int i = 0; i < 16; ++i) mask[k * 16 + i] = 0u;   // 8192 words
    if (k == 0) *lossAdj = 0.f;
}

__global__ __launch_bounds__(NTHREADS, 2) void vq_main(
    const float* __restrict__ x, const float* __restrict__ emb,
    const float* __restrict__ g_esq,
    const unsigned short* __restrict__ eh_g, const unsigned short* __restrict__ el_g,
    unsigned short* __restrict__ g_idx, float* __restrict__ g_lossPart,
    unsigned* __restrict__ g_mask, float* __restrict__ out)
{
    __shared__ float xs[MT * XS_STRIDE];                  // 17.4 KB, row-major x tile
    __shared__ unsigned short ehs[128 * ES_STRIDE];       // 18.4 KB codebook chunk hi
    __shared__ unsigned short els[128 * ES_STRIDE];       // 18.4 KB codebook chunk lo
    __shared__ float esq_s[KCODES];                       // 2 KB
    __shared__ int   idx_s[MT];
    __shared__ int   flg_s[MT];
    __shared__ float wred[4];

    const int tid  = threadIdx.x;
    const int R0   = blockIdx.x * MT;
    const int w    = tid >> 6;          // wave 0..3 -> rows w*16..w*16+15
    const int lane = tid & 63;
    const int m    = lane & 15;         // A-frag row / B-frag col / C col
    const int q    = lane >> 4;         // quad: k-run selector / C row group

    // ---- stage x tile (coalesced float4, row-major stride 68) ----
    #pragma unroll
    for (int i = 0; i < 4; ++i) {
        int flat = tid + NTHREADS * i;          // 0..1023
        int r  = flat >> 4;
        int qc = flat & 15;
        f32x4 v = *(const f32x4*)&x[(size_t)(R0 + r) * DIM + 4 * qc];
        *(f32x4*)&xs[r * XS_STRIDE + 4 * qc] = v;
    }
    esq_s[tid]       = g_esq[tid];
    esq_s[tid + 256] = g_esq[tid + 256];
    __syncthreads();

    // ---- A-frags (register-resident): rows w*16+m, k = kc*32 + q*8 + t ----
    s16x8 axh[2], axl[2];
    const int lrow = w * 16 + m;
    #pragma unroll
    for (int kc = 0; kc < 2; ++kc) {
        const float* px = &xs[lrow * XS_STRIDE + kc * 32 + q * 8];
        s16x8 h, l;
        #pragma unroll
        for (int t = 0; t < 8; ++t) {
            float v = px[t];
            unsigned short hb = f2bf(v);
            h[t] = (short)hb;
            l[t] = (short)f2bf(v - bf2f(hb));
        }
        axh[kc] = h; axl[kc] = l;
    }

    f32x4 acc[32];                                      // 512 codes per 16 rows
    #pragma unroll
    for (int a = 0; a < 32; ++a) acc[a] = (f32x4){0.f, 0.f, 0.f, 0.f};

    // ---- 4 chunks of 128 codes ----
    for (int c = 0; c < 4; ++c) {
        if (c) __syncthreads();                          // prior chunk reads done
        #pragma unroll
        for (int i = 0; i < 4; ++i) {                    // stage chunk: coalesced 16B
            int ch = tid + NTHREADS * i;                 // 0..1023
            int rl = ch >> 3, off = (ch & 7) * 8;
            size_t gofs = (size_t)(c * 128 + rl) * DIM + off;
            *(s16x8*)&ehs[rl * ES_STRIDE + off] = *(const s16x8*)&eh_g[gofs];
            *(s16x8*)&els[rl * ES_STRIDE + off] = *(const s16x8*)&el_g[gofs];
        }
        __syncthreads();
        #pragma unroll
        for (int ct = 0; ct < 8; ++ct) {
            const int a = c * 8 + ct;
            #pragma unroll
            for (int kc = 0; kc < 2; ++kc) {
                const int bofs = (ct * 16 + m) * ES_STRIDE + kc * 32 + q * 8;
                s16x8 bh = *(const s16x8*)&ehs[bofs];
                s16x8 bl = *(const s16x8*)&els[bofs];
                acc[a] = __builtin_amdgcn_mfma_f32_16x16x32_bf16(axh[kc], bh, acc[a], 0, 0, 0);
                acc[a] = __builtin_amdgcn_mfma_f32_16x16x32_bf16(axl[kc], bh, acc[a], 0, 0, 0);
                acc[a] = __builtin_amdgcn_mfma_f32_16x16x32_bf16(axh[kc], bl, acc[a], 0, 0, 0);
            }
        }
    }

    // ---- per-row argmin + second-best (C layout: row=q*4+r, col=a*16+m) ----
    float b1[4], b2[4]; int i1[4];
    #pragma unroll
    for (int r = 0; r < 4; ++r) { b1[r] = 3.4e38f; b2[r] = 3.4e38f; i1[r] = 0; }
    #pragma unroll
    for (int a = 0; a < 32; ++a) {
        int col = a * 16 + m;                            // ascending in a
        float e2 = esq_s[col];
        #pragma unroll
        for (int r = 0; r < 4; ++r) {
            float dist = e2 - 2.f * acc[a][r];
            if (dist < b1[r]) { b2[r] = b1[r]; b1[r] = dist; i1[r] = col; }
            else if (dist < b2[r]) b2[r] = dist;
        }
    }
    #pragma unroll
    for (int s = 1; s < 16; s <<= 1) {                   // butterfly within 16-lane group
        #pragma unroll
        for (int r = 0; r < 4; ++r) {
            float ob1 = __shfl_xor(b1[r], s);
            int   oi1 = __shfl_xor(i1[r], s);
            float ob2 = __shfl_xor(b2[r], s);
            bool owin = (ob1 < b1[r]) || (ob1 == b1[r] && oi1 < i1[r]);
            float lb1 = owin ? b1[r] : ob1;              // loser's best = new 2nd candidate
            b2[r] = fminf(fminf(b2[r], ob2), lb1);
            if (owin) { b1[r] = ob1; i1[r] = oi1; }
        }
    }
    if (m == 0) {
        #pragma unroll
        for (int r = 0; r < 4; ++r) {
            int lrw = w * 16 + q * 4 + r;
            idx_s[lrw] = i1[r];
            int f = (b2[r] - b1[r] < MARGIN) ? 1 : 0;
            flg_s[lrw] = f;
            if (f) {
                int grow = R0 + lrw;
                atomicOr(&g_mask[grow >> 5], 1u << (grow & 31));   // rare
            }
        }
    }
    __syncthreads();
    // per-row index out (placeholder for flagged rows; cleanup overwrites)
    if (tid < MT) g_idx[R0 + tid] = (unsigned short)idx_s[tid];

    // ---- epilogue: q_st + loss for unflagged rows (round-1 op order) ----
    const int r  = tid >> 2;
    const int d0 = (tid & 3) * 16;
    float lpart = 0.f;
    if (!flg_s[r]) {
        const int ki = idx_s[r];
        const float* erow = emb + (size_t)ki * DIM;
        #pragma unroll
        for (int s4 = 0; s4 < 4; ++s4) {
            int d = d0 + 4 * s4;
            f32x4 e4 = *(const f32x4*)&erow[d];
            float xv0 = xs[r * XS_STRIDE + d + 0];
            float xv1 = xs[r * XS_STRIDE + d + 1];
            float xv2 = xs[r * XS_STRIDE + d + 2];
            float xv3 = xs[r * XS_STRIDE + d + 3];
            float f0 = e4.x - xv0, f1 = e4.y - xv1, f2 = e4.z - xv2, f3 = e4.w - xv3;
            f32x4 o = {xv0 + f0, xv1 + f1, xv2 + f2, xv3 + f3};
            *(f32x4*)&out[(size_t)(R0 + r) * DIM + d] = o;
            lpart += f0*f0 + f1*f1 + f2*f2 + f3*f3;
        }
    }
    #pragma unroll
    for (int off = 32; off > 0; off >>= 1) lpart += __shfl_down(lpart, off);
    if ((tid & 63) == 0) wred[tid >> 6] = lpart;
    __syncthreads();
    if (tid == 0) g_lossPart[blockIdx.x] = wred[0] + wred[1] + wred[2] + wred[3];
}

// Exact fp32 re-resolution of flagged rows — replicates round-1 math bit-for-bit.
__global__ __launch_bounds__(256) void vq_cleanup(
    const float* __restrict__ x, const float* __restrict__ emb,
    const float* __restrict__ g_esq, unsigned short* __restrict__ g_idx,
    float* __restrict__ lossAdj, const unsigned* __restrict__ g_mask,
    float* __restrict__ out)
{
    int w    = blockIdx.x * 4 + (threadIdx.x >> 6);   // 0..4095, 64 rows each
    int lane = threadIdx.x & 63;
    unsigned m0 = g_mask[w * 2], m1 = g_mask[w * 2 + 1];
    unsigned long long bits = ((unsigned long long)m1 << 32) | m0;
    while (bits) {
        int b = __ffsll((unsigned long long)bits) - 1;
        bits &= bits - 1;
        int row = w * 64 + b;
        const float* xr = &x[(size_t)row * DIM];
        float best = 3.4e38f; int bidx = 0;
        #pragma unroll
        for (int j = 0; j < 8; ++j) {
            int c = lane * 8 + j;
            const float* er = &emb[(size_t)c * DIM];
            float dot = 0.f;
            #pragma unroll
            for (int d = 0; d < DIM; ++d) dot = fmaf(xr[d], er[d], dot);
            float dist = g_esq[c] - 2.f * dot;         // round-1 formula/order
            if (dist < best) { best = dist; bidx = c; }
        }
        #pragma unroll
        for (int s = 1; s < 64; s <<= 1) {
            float ob = __shfl_xor(best, s);
            int   oi = __shfl_xor(bidx, s);
            if (ob < best || (ob == best && oi < bidx)) { best = ob; bidx = oi; }
        }
        float xv = xr[lane];
        float ev = emb[(size_t)bidx * DIM + lane];
        float f  = ev - xv;
        out[(size_t)row * DIM + lane] = xv + f;
        float lp = f * f;
        #pragma unroll
        for (int s = 1; s < 64; s <<= 1) lp += __shfl_xor(lp, s);
        if (lane == 0) {
            atomicAdd(lossAdj, lp);                    // rare (~tens of rows total)
            g_idx[row] = (unsigned short)bidx;
        }
    }
}

// Low-contention histogram: LDS per-block, then <=512 global adds per block.
__global__ __launch_bounds__(256) void vq_hist(const unsigned short* __restrict__ g_idx,
                                               int* __restrict__ counts) {
    __shared__ int h[KCODES];
    int t = threadIdx.x;
    h[t] = 0; h[t + 256] = 0;
    __syncthreads();
    const unsigned short* p = g_idx + (size_t)blockIdx.x * 4096;
    #pragma unroll
    for (int i = 0; i < 16; ++i)
        atomicAdd(&h[p[t + 256 * i]], 1);
    __syncthreads();
    int v0 = h[t], v1 = h[t + 256];
    if (v0) atomicAdd(&counts[t], v0);
    if (v1) atomicAdd(&counts[t + 256], v1);
}

__global__ __launch_bounds__(512) void vq_final(const int* __restrict__ counts,
                                                const float* __restrict__ lossPart,
                                                const float* __restrict__ lossAdj,
                                                float* __restrict__ out) {
    __shared__ float redp[8];
    __shared__ float redl[8];
    int k = threadIdx.x;
    float p = (float)counts[k] * (1.f / 262144.f);
    float t = p * logf(p + 1e-10f);
    float l = 0.f;
    #pragma unroll
    for (int i = 0; i < 8; ++i) l += lossPart[k + 512 * i];
    #pragma unroll
    for (int off = 32; off > 0; off >>= 1) {
        t += __shfl_down(t, off);
        l += __shfl_down(l, off);
    }
    if ((k & 63) == 0) { redp[k >> 6] = t; redl[k >> 6] = l; }
    __syncthreads();
    if (k == 0) {
        float s = 0.f, ls = 0.f;
        #pragma unroll
        for (int i = 0; i < 8; ++i) { s += redp[i]; ls += redl[i]; }
        out[16777216] = (ls + *lossAdj) * (0.25f / 16777216.f);
        out[16777217] = expf(-s);
    }
}

extern "C" void kernel_launch(void* const* d_in, const int* in_sizes, int n_in,
                              void* d_out, int out_size, void* d_ws, size_t ws_size,
                              hipStream_t stream) {
    const float* x   = (const float*)d_in[0];
    const float* emb = (const float*)d_in[1];
    float* out = (float*)d_out;

    char* ws = (char*)d_ws;
    float*          esq      = (float*)(ws + 0);
    int*            counts   = (int*)(ws + 2048);
    float*          lossAdj  = (float*)(ws + 4096);
    unsigned short* eh       = (unsigned short*)(ws + 4608);
    unsigned short* el       = (unsigned short*)(ws + 70144);
    unsigned*       mask     = (unsigned*)(ws + 135680);
    unsigned short* gidx     = (unsigned short*)(ws + 168448);
    float*          lossPart = (float*)(ws + 692736);

    vq_prep<<<1, 512, 0, stream>>>(emb, esq, counts, lossAdj, eh, el, mask);
    vq_main<<<NBLOCKS, NTHREADS, 0, stream>>>(x, emb, esq, eh, el,
                                              gidx, lossPart, mask, out);
    vq_cleanup<<<1024, 256, 0, stream>>>(x, emb, esq, gidx, lossAdj, mask, out);
    vq_hist<<<64, 256, 0, stream>>>(gidx, counts);
    vq_final<<<1, 512, 0, stream>>>(counts, lossPart, lossAdj, out);
}